// Round 3
// baseline (222.682 us; speedup 1.0000x reference)
//
#include <hip/hip_runtime.h>
#include <hip/hip_cooperative_groups.h>
#include <math.h>

namespace cg = cooperative_groups;

#define Bn 32
#define Hc 32
#define Ln 32768
#define RELC 2
#define IMC 4
#define OC 8
#define CATC 16
#define KS 7
#define NPOS (Bn*Ln)
#define TPB 256
#define VPT 4
#define PPB (TPB*VPT)          // 1024 positions per block
#define TILES (Ln/PPB)         // 32
#define NBLK (Bn*TILES)        // 1024 blocks = 4/CU * 256 CU exactly
#define NSLOT 32
#define SSTR 128               // doubles per stat slot

// ---- coop slotted stat indices (slot-relative) ----
#define iS_PHI 0   // [0..1] S_phi, [2..3] SS_phi, [4..5] S_psi, [6..7] SS_psi
#define iS_T   8   // [8..11] S_t, [12..15] SS_t
#define iS_AP  16  // [16..23] S_ap, [24..31] SS_ap
#define iS_Y   32  // 32 channels
#define iSS_Y  64  // 32 channels
// coop bstats (psi boundary corrections, unslotted)
#define bPF  0
#define bPFS 6
#define bQL  12
#define bQLS 18
#define NBST 24

// ---- fallback stat layout (doubles at d_ws[0..]) ----
#define S_PHI  0
#define SS_PHI 2
#define S_PSI  4
#define SS_PSI 6
#define PF     8
#define PFS    14
#define QL     20
#define QLS    26
#define S_T    32
#define SS_T   36
#define S_AP   40
#define SS_AP  48
#define S_Y    56
#define SS_Y   88
#define NSTATS 120

#define FMA4(A,S,V) { A.x=fmaf((S),(V).x,A.x); A.y=fmaf((S),(V).y,A.y); A.z=fmaf((S),(V).z,A.z); A.w=fmaf((S),(V).w,A.w); }

__device__ inline float4 affrelu(float4 v, float a, float d){
    float4 r;
    r.x=fmaxf(fmaf(a,v.x,d),0.f); r.y=fmaxf(fmaf(a,v.y,d),0.f);
    r.z=fmaxf(fmaf(a,v.z,d),0.f); r.w=fmaxf(fmaf(a,v.w,d),0.f);
    return r;
}
__device__ inline double wredd(double v){
    #pragma unroll
    for (int o=32;o>0;o>>=1) v += __shfl_down(v,o,64);
    return v;
}
__device__ inline float wredf(float v){
    #pragma unroll
    for (int o=32;o>0;o>>=1) v += __shfl_down(v,o,64);
    return v;
}
__device__ inline void atomAddD(double* p, double v){ unsafeAtomicAdd(p, v); }
__device__ inline void aaddd(double* p, double v){
    __hip_atomic_fetch_add(p, v, __ATOMIC_RELAXED, __HIP_MEMORY_SCOPE_AGENT);
}
__device__ inline double aload(const double* p){
    return __hip_atomic_load(p, __ATOMIC_RELAXED, __HIP_MEMORY_SCOPE_AGENT);
}
__device__ inline void astoref(float* p, float v){
    __hip_atomic_store(p, v, __ATOMIC_RELAXED, __HIP_MEMORY_SCOPE_AGENT);
}
__device__ inline float aloadf(const float* p){
    return __hip_atomic_load(p, __ATOMIC_RELAXED, __HIP_MEMORY_SCOPE_AGENT);
}

struct P {
    const float *x;
    const float *w_phi,*b_phi,*w_psi,*b_psi,*w_beta,*b_beta;
    const float *w_cw1,*b_cw1,*w_cw2,*b_cw2,*w_out,*b_out;
    const float *g_cat,*be_cat,*g_im,*be_im,*g_ag,*be_ag,*g_hid,*be_hid;
    float *out;
    double *stats, *bstats;
    float *halo;
};

// ======================= fused cooperative kernel =======================
__global__ void __launch_bounds__(TPB, 4) fused(P p)
{
    cg::grid_group gg = cg::this_grid();
    __shared__ __align__(16) float wsm[512];
    __shared__ __align__(16) float psiT[2][PPB+16];
    __shared__ float affA[32], affD[32];
    __shared__ float w1s[IMC*CATC], b1s[IMC], w2s[OC*IMC], b2s[OC];
    __shared__ double rbuf[4][16];
    __shared__ float fredS[Hc][4], fredQ[Hc][4];

    const int tid=threadIdx.x, lane=tid&63, wid=tid>>6;
    const int bidx=blockIdx.x, b=bidx/TILES, tile=bidx%TILES;
    const int slot=bidx & (NSLOT-1);
    const int li=tid*VPT;
    const double N=(double)NPOS;
    double* st = p.stats + (size_t)slot*SSTR;
    const float* xb = p.x + (size_t)b*Hc*Ln + (size_t)tile*PPB + li;

    // ---- stage 1: x -> phi,psi,beta ----
    for (int i=tid;i<Hc*12;i+=TPB){
        int h=i/12, j=i%12;
        float v;
        if (j<2)      v=p.w_phi[j*Hc+h];
        else if (j<4) v=p.w_psi[(j-2)*Hc+h];
        else          v=p.w_beta[(j-4)*Hc+h];
        wsm[h*12+j]=v;
    }
    if (tid<12) wsm[Hc*12+tid] = (tid<2)?p.b_phi[tid]:(tid<4)?p.b_psi[tid-2]:p.b_beta[tid-4];
    __syncthreads();

    float4 acc[12];
    #pragma unroll
    for (int j=0;j<12;++j){ float bb=wsm[Hc*12+j]; acc[j]=make_float4(bb,bb,bb,bb); }
    #pragma unroll 4
    for (int h=0;h<Hc;++h){
        const float4 xv=*(const float4*)(xb+(size_t)h*Ln);
        const float4 w0=*(const float4*)&wsm[h*12+0];
        const float4 w1=*(const float4*)&wsm[h*12+4];
        const float4 w2=*(const float4*)&wsm[h*12+8];
        FMA4(acc[0],w0.x,xv); FMA4(acc[1],w0.y,xv); FMA4(acc[2],w0.z,xv); FMA4(acc[3],w0.w,xv);
        FMA4(acc[4],w1.x,xv); FMA4(acc[5],w1.y,xv); FMA4(acc[6],w1.z,xv); FMA4(acc[7],w1.w,xv);
        FMA4(acc[8],w2.x,xv); FMA4(acc[9],w2.y,xv); FMA4(acc[10],w2.z,xv); FMA4(acc[11],w2.w,xv);
    }
    *(float4*)&psiT[0][4+li] = acc[2];
    *(float4*)&psiT[1][4+li] = acc[3];
    if (tid==0){
        #pragma unroll
        for (int c=0;c<2;++c){
            float pv[4]={acc[2+c].x,acc[2+c].y,acc[2+c].z,acc[2+c].w};
            #pragma unroll
            for (int i=0;i<3;++i) astoref(&p.halo[((size_t)bidx*2+c)*8+i], pv[i]);
            if (tile==0)
                for (int i=0;i<3;++i){ aaddd(&p.bstats[bPF+c*3+i],(double)pv[i]); aaddd(&p.bstats[bPFS+c*3+i],(double)pv[i]*pv[i]); }
        }
    }
    if (tid==TPB-1){
        #pragma unroll
        for (int c=0;c<2;++c){
            float pv[4]={acc[2+c].x,acc[2+c].y,acc[2+c].z,acc[2+c].w};
            #pragma unroll
            for (int i=0;i<3;++i) astoref(&p.halo[((size_t)bidx*2+c)*8+4+i], pv[i+1]);
            if (tile==TILES-1)
                for (int i=0;i<3;++i){ aaddd(&p.bstats[bQL+c*3+i],(double)pv[i+1]); aaddd(&p.bstats[bQLS+c*3+i],(double)pv[i+1]*pv[i+1]); }
        }
    }
    {
        double vals[8];
        #pragma unroll
        for (int c=0;c<2;++c){
            float4 v=acc[c], u=acc[2+c];
            vals[c]  =(double)v.x+v.y+v.z+v.w;
            vals[2+c]=(double)v.x*v.x+(double)v.y*v.y+(double)v.z*v.z+(double)v.w*v.w;
            vals[4+c]=(double)u.x+u.y+u.z+u.w;
            vals[6+c]=(double)u.x*u.x+(double)u.y*u.y+(double)u.z*u.z+(double)u.w*u.w;
        }
        #pragma unroll
        for (int i=0;i<8;++i){ double r=wredd(vals[i]); if(lane==0) rbuf[wid][i]=r; }
        __syncthreads();
        if (tid<8) aaddd(&st[iS_PHI+tid], rbuf[0][tid]+rbuf[1][tid]+rbuf[2][tid]+rbuf[3][tid]);
    }
    gg.sync();

    // ---- stage 3: BN_cat + relu + conv_cw1 -> t ----
    if (tid<IMC*CATC) w1s[tid]=p.w_cw1[tid];
    if (tid<IMC)      b1s[tid]=p.b_cw1[tid];
    if (tid<CATC){
        int ch=tid; double S=0,SS=0;
        if (ch<2){
            for (int s=0;s<NSLOT;++s){ S+=aload(&p.stats[(size_t)s*SSTR+0+ch]); SS+=aload(&p.stats[(size_t)s*SSTR+2+ch]); }
        } else {
            int c=(ch-2)/KS, j=(ch-2)%KS, d=j-KS/2;
            for (int s=0;s<NSLOT;++s){ S+=aload(&p.stats[(size_t)s*SSTR+4+c]); SS+=aload(&p.stats[(size_t)s*SSTR+6+c]); }
            if (d>0) for (int i=0;i<d;++i)   { S-=aload(&p.bstats[bPF+c*3+i]);  SS-=aload(&p.bstats[bPFS+c*3+i]); }
            if (d<0) for (int i=3+d;i<3;++i) { S-=aload(&p.bstats[bQL+c*3+i]);  SS-=aload(&p.bstats[bQLS+c*3+i]); }
        }
        double m=S/N, v=SS/N-m*m, inv=1.0/sqrt(v+1e-5);
        affA[ch]=(float)(p.g_cat[ch]*inv);
        affD[ch]=p.be_cat[ch]-(float)(m*inv*p.g_cat[ch]);
    }
    if (tid>=64 && tid<70){ int k=tid-64, c=k/3, i=k%3;
        psiT[c][1+i]    = (tile>0)       ? aloadf(&p.halo[((size_t)(bidx-1)*2+c)*8+4+i]) : 0.f; }
    if (tid>=70 && tid<76){ int k=tid-70, c=k/3, i=k%3;
        psiT[c][1028+i] = (tile<TILES-1) ? aloadf(&p.halo[((size_t)(bidx+1)*2+c)*8+i])   : 0.f; }
    __syncthreads();

    float4 tacc[IMC];
    #pragma unroll
    for (int o=0;o<IMC;++o){ float bb=b1s[o]; tacc[o]=make_float4(bb,bb,bb,bb); }
    #pragma unroll
    for (int c=0;c<RELC;++c){
        float4 hv=affrelu(acc[c],affA[c],affD[c]);
        #pragma unroll
        for (int o=0;o<IMC;++o) FMA4(tacc[o],w1s[o*CATC+c],hv);
    }
    #pragma unroll
    for (int c=0;c<RELC;++c){
        float4 A0=*(const float4*)&psiT[c][li];
        float4 A1=*(const float4*)&psiT[c][li+4];
        float4 A2=*(const float4*)&psiT[c][li+8];
        float pr[10]={A0.y,A0.z,A0.w,A1.x,A1.y,A1.z,A1.w,A2.x,A2.y,A2.z};
        #pragma unroll
        for (int j=0;j<KS;++j){
            int ch=2+c*KS+j;
            float a=affA[ch], d=affD[ch];
            float4 hv;
            hv.x=fmaxf(fmaf(a,pr[j+0],d),0.f);
            hv.y=fmaxf(fmaf(a,pr[j+1],d),0.f);
            hv.z=fmaxf(fmaf(a,pr[j+2],d),0.f);
            hv.w=fmaxf(fmaf(a,pr[j+3],d),0.f);
            #pragma unroll
            for (int o=0;o<IMC;++o) FMA4(tacc[o],w1s[o*CATC+ch],hv);
        }
    }
    {
        double vals[8];
        #pragma unroll
        for (int o=0;o<IMC;++o){
            float4 v=tacc[o];
            vals[o]  =(double)v.x+v.y+v.z+v.w;
            vals[4+o]=(double)v.x*v.x+(double)v.y*v.y+(double)v.z*v.z+(double)v.w*v.w;
        }
        #pragma unroll
        for (int i=0;i<8;++i){ double r=wredd(vals[i]); if(lane==0) rbuf[wid][i]=r; }
        __syncthreads();
        if (tid<8) aaddd(&st[iS_T+tid], rbuf[0][tid]+rbuf[1][tid]+rbuf[2][tid]+rbuf[3][tid]);
    }
    gg.sync();

    // ---- stage 5: BN_im + relu + conv_cw2, *beta -> ap ----
    if (tid<OC*IMC) w2s[tid]=p.w_cw2[tid];
    if (tid<OC)     b2s[tid]=p.b_cw2[tid];
    if (tid<IMC){
        double S=0,SS=0;
        for (int s=0;s<NSLOT;++s){ S+=aload(&p.stats[(size_t)s*SSTR+iS_T+tid]); SS+=aload(&p.stats[(size_t)s*SSTR+iS_T+IMC+tid]); }
        double m=S/N, v=SS/N-m*m, inv=1.0/sqrt(v+1e-5);
        affA[tid]=(float)(p.g_im[tid]*inv);
        affD[tid]=p.be_im[tid]-(float)(m*inv*p.g_im[tid]);
    }
    __syncthreads();
    float4 ap[OC];
    {
        float4 h2[IMC];
        #pragma unroll
        for (int i=0;i<IMC;++i) h2[i]=affrelu(tacc[i],affA[i],affD[i]);
        #pragma unroll
        for (int o=0;o<OC;++o){
            float bb=b2s[o];
            float4 w=make_float4(bb,bb,bb,bb);
            #pragma unroll
            for (int i=0;i<IMC;++i) FMA4(w,w2s[o*IMC+i],h2[i]);
            float4 bv=acc[4+o];
            ap[o].x=w.x*bv.x; ap[o].y=w.y*bv.y; ap[o].z=w.z*bv.z; ap[o].w=w.w*bv.w;
        }
    }
    {
        double vals[16];
        #pragma unroll
        for (int o=0;o<OC;++o){
            float4 v=ap[o];
            vals[o]  =(double)v.x+v.y+v.z+v.w;
            vals[8+o]=(double)v.x*v.x+(double)v.y*v.y+(double)v.z*v.z+(double)v.w*v.w;
        }
        #pragma unroll
        for (int i=0;i<16;++i){ double r=wredd(vals[i]); if(lane==0) rbuf[wid][i]=r; }
        __syncthreads();
        if (tid<16) aaddd(&st[iS_AP+tid], rbuf[0][tid]+rbuf[1][tid]+rbuf[2][tid]+rbuf[3][tid]);
    }
    gg.sync();

    // ---- stage 7: ag = relu(BN_aggr(ap)); y stats ----
    wsm[tid]=p.w_out[tid];
    if (tid<Hc) wsm[256+tid]=p.b_out[tid];
    if (tid<OC){
        double S=0,SS=0;
        for (int s=0;s<NSLOT;++s){ S+=aload(&p.stats[(size_t)s*SSTR+iS_AP+tid]); SS+=aload(&p.stats[(size_t)s*SSTR+iS_AP+OC+tid]); }
        double m=S/N, v=SS/N-m*m, inv=1.0/sqrt(v+1e-5);
        affA[tid]=(float)(p.g_ag[tid]*inv);
        affD[tid]=p.be_ag[tid]-(float)(m*inv*p.g_ag[tid]);
    }
    __syncthreads();
    float4 ag[OC];
    #pragma unroll
    for (int o=0;o<OC;++o) ag[o]=affrelu(ap[o],affA[o],affD[o]);
    #pragma unroll 4
    for (int h=0;h<Hc;++h){
        float4 y=*(const float4*)(xb+(size_t)h*Ln);
        float bb=wsm[256+h];
        y.x+=bb; y.y+=bb; y.z+=bb; y.w+=bb;
        #pragma unroll
        for (int o=0;o<OC;++o) FMA4(y,wsm[h*OC+o],ag[o]);
        float fs=y.x+y.y+y.z+y.w;
        float fq=y.x*y.x+y.y*y.y+y.z*y.z+y.w*y.w;
        fs=wredf(fs); fq=wredf(fq);
        if (lane==0){ fredS[h][wid]=fs; fredQ[h][wid]=fq; }
    }
    __syncthreads();
    if (tid<Hc){
        double s=(double)fredS[tid][0]+fredS[tid][1]+fredS[tid][2]+fredS[tid][3];
        double q=(double)fredQ[tid][0]+fredQ[tid][1]+fredQ[tid][2]+fredQ[tid][3];
        aaddd(&st[iS_Y+tid], s);
        aaddd(&st[iSS_Y+tid], q);
    }
    gg.sync();

    // ---- stage 9: recompute y, BN_hid + relu -> out ----
    if (tid<Hc){
        double S=0,SS=0;
        for (int s=0;s<NSLOT;++s){ S+=aload(&p.stats[(size_t)s*SSTR+iS_Y+tid]); SS+=aload(&p.stats[(size_t)s*SSTR+iSS_Y+tid]); }
        double m=S/N, v=SS/N-m*m, inv=1.0/sqrt(v+1e-5);
        affA[tid]=(float)(p.g_hid[tid]*inv);
        affD[tid]=p.be_hid[tid]-(float)(m*inv*p.g_hid[tid]);
    }
    __syncthreads();
    float* ob = p.out + (size_t)b*Hc*Ln + (size_t)tile*PPB + li;
    #pragma unroll 4
    for (int h=0;h<Hc;++h){
        float4 y=*(const float4*)(xb+(size_t)h*Ln);
        float bb=wsm[256+h];
        y.x+=bb; y.y+=bb; y.z+=bb; y.w+=bb;
        #pragma unroll
        for (int o=0;o<OC;++o) FMA4(y,wsm[h*OC+o],ag[o]);
        *(float4*)(ob+(size_t)h*Ln)=affrelu(y,affA[h],affD[h]);
    }
}

// ======================= fallback: 5-kernel path (round-1, known-pass) =======================
__global__ void __launch_bounds__(TPB) k1(
    const float* __restrict__ x,
    const float* __restrict__ w_phi, const float* __restrict__ b_phi,
    const float* __restrict__ w_psi, const float* __restrict__ b_psi,
    const float* __restrict__ w_beta,const float* __restrict__ b_beta,
    float* __restrict__ phi, float* __restrict__ psi, float* __restrict__ beta,
    double* __restrict__ stats)
{
    __shared__ __align__(16) float wl[Hc*12 + 12];
    __shared__ double rbuf[4][8];
    const int tid = threadIdx.x;
    for (int i = tid; i < Hc*12; i += TPB) {
        int h = i/12, j = i%12;
        float v;
        if (j < 2)      v = w_phi[j*Hc + h];
        else if (j < 4) v = w_psi[(j-2)*Hc + h];
        else            v = w_beta[(j-4)*Hc + h];
        wl[h*12 + j] = v;
    }
    if (tid < 12)
        wl[Hc*12+tid] = (tid<2) ? b_phi[tid] : (tid<4) ? b_psi[tid-2] : b_beta[tid-4];
    __syncthreads();

    const int b    = blockIdx.x / TILES;
    const int tile = blockIdx.x % TILES;
    const int l0   = tile*PPB + tid*VPT;

    float4 acc[12];
    #pragma unroll
    for (int j=0;j<12;++j){ float bb = wl[Hc*12+j]; acc[j]=make_float4(bb,bb,bb,bb); }

    const float* xb = x + (size_t)b*Hc*Ln + l0;
    #pragma unroll 4
    for (int h=0; h<Hc; ++h) {
        const float4 xv = *(const float4*)(xb + (size_t)h*Ln);
        const float4 w0 = *(const float4*)(&wl[h*12+0]);
        const float4 w1 = *(const float4*)(&wl[h*12+4]);
        const float4 w2 = *(const float4*)(&wl[h*12+8]);
        FMA4(acc[0],w0.x,xv); FMA4(acc[1],w0.y,xv); FMA4(acc[2],w0.z,xv); FMA4(acc[3],w0.w,xv);
        FMA4(acc[4],w1.x,xv); FMA4(acc[5],w1.y,xv); FMA4(acc[6],w1.z,xv); FMA4(acc[7],w1.w,xv);
        FMA4(acc[8],w2.x,xv); FMA4(acc[9],w2.y,xv); FMA4(acc[10],w2.z,xv); FMA4(acc[11],w2.w,xv);
    }
    #pragma unroll
    for (int c=0;c<RELC;++c) *(float4*)(phi + ((size_t)(b*RELC+c))*Ln + l0) = acc[c];
    #pragma unroll
    for (int c=0;c<RELC;++c) *(float4*)(psi + ((size_t)(b*RELC+c))*Ln + l0) = acc[2+c];
    #pragma unroll
    for (int o=0;o<OC;++o)   *(float4*)(beta + ((size_t)(b*OC+o))*Ln + l0)  = acc[4+o];

    double vals[8];
    #pragma unroll
    for (int c=0;c<2;++c){
        float4 v = acc[c];
        vals[c]   = (double)v.x+v.y+v.z+v.w;
        vals[2+c] = (double)v.x*v.x+(double)v.y*v.y+(double)v.z*v.z+(double)v.w*v.w;
        float4 u = acc[2+c];
        vals[4+c] = (double)u.x+u.y+u.z+u.w;
        vals[6+c] = (double)u.x*u.x+(double)u.y*u.y+(double)u.z*u.z+(double)u.w*u.w;
    }
    if (tile==0 || tile==TILES-1) {
        #pragma unroll
        for (int c=0;c<2;++c){
            const float pv[4] = {acc[2+c].x, acc[2+c].y, acc[2+c].z, acc[2+c].w};
            #pragma unroll
            for (int e=0;e<4;++e){
                int le = l0+e;
                if (le < 3) {
                    atomAddD(&stats[PF +c*3+le], (double)pv[e]);
                    atomAddD(&stats[PFS+c*3+le], (double)pv[e]*pv[e]);
                }
                if (le >= Ln-3) {
                    int i = le-(Ln-3);
                    atomAddD(&stats[QL +c*3+i], (double)pv[e]);
                    atomAddD(&stats[QLS+c*3+i], (double)pv[e]*pv[e]);
                }
            }
        }
    }
    const int lane=tid&63, wid=tid>>6;
    #pragma unroll
    for (int i=0;i<8;++i){ double r=wredd(vals[i]); if(lane==0) rbuf[wid][i]=r; }
    __syncthreads();
    if (tid<8) atomAddD(&stats[tid], rbuf[0][tid]+rbuf[1][tid]+rbuf[2][tid]+rbuf[3][tid]);
}

__global__ void __launch_bounds__(TPB) k3(
    const float* __restrict__ phi, const float* __restrict__ psi,
    const float* __restrict__ w_cw1, const float* __restrict__ b_cw1,
    const float* __restrict__ g_cat, const float* __restrict__ be_cat,
    float* __restrict__ tbuf, double* __restrict__ stats)
{
    __shared__ float aA[CATC], aD[CATC];
    __shared__ float w1[IMC*CATC], b1[IMC];
    __shared__ __align__(16) float psiT[2][1032];
    __shared__ double rbuf[4][8];
    const int tid = threadIdx.x;
    if (tid==0) {
        const double N = (double)NPOS;
        for (int ch=0; ch<CATC; ++ch) {
            double S, SS;
            if (ch < 2) { S = stats[S_PHI+ch]; SS = stats[SS_PHI+ch]; }
            else {
                int c=(ch-2)/KS, j=(ch-2)%KS, d=j-KS/2;
                S = stats[S_PSI+c]; SS = stats[SS_PSI+c];
                if (d>0) for (int i=0;i<d;++i)   { S -= stats[PF +c*3+i]; SS -= stats[PFS+c*3+i]; }
                if (d<0) for (int i=3+d;i<3;++i) { S -= stats[QL +c*3+i]; SS -= stats[QLS+c*3+i]; }
            }
            double m=S/N, v=SS/N - m*m;
            double inv = 1.0/sqrt(v + 1e-5);
            aA[ch]=(float)(g_cat[ch]*inv);
            aD[ch]=be_cat[ch] - (float)(m*inv*g_cat[ch]);
        }
    }
    if (tid < IMC*CATC) w1[tid] = w_cw1[tid];
    if (tid < IMC)      b1[tid] = b_cw1[tid];

    const int b    = blockIdx.x / TILES;
    const int tile = blockIdx.x % TILES;
    const int lb   = tile*PPB;
    #pragma unroll
    for (int c=0;c<2;++c)
        for (int idx=tid; idx<1032; idx+=TPB) {
            int l = lb - 3 + idx;
            psiT[c][idx] = (l>=0 && l<Ln && idx<1030) ? psi[((size_t)(b*RELC+c))*Ln + l] : 0.f;
        }
    __syncthreads();

    const int li = tid*VPT;
    const int l  = lb + li;
    float4 tacc[IMC];
    #pragma unroll
    for (int o=0;o<IMC;++o){ float bb=b1[o]; tacc[o]=make_float4(bb,bb,bb,bb); }

    #pragma unroll
    for (int c=0;c<2;++c){
        float4 p = *(const float4*)(phi + ((size_t)(b*RELC+c))*Ln + l);
        float4 hv = affrelu(p, aA[c], aD[c]);
        #pragma unroll
        for (int o=0;o<IMC;++o) FMA4(tacc[o], w1[o*CATC+c], hv);
    }
    #pragma unroll
    for (int c=0;c<2;++c){
        float4 A  = *(const float4*)&psiT[c][li];
        float4 Bv = *(const float4*)&psiT[c][li+4];
        float4 Cv = *(const float4*)&psiT[c][li+8];
        float pr[12] = {A.x,A.y,A.z,A.w, Bv.x,Bv.y,Bv.z,Bv.w, Cv.x,Cv.y,Cv.z,Cv.w};
        #pragma unroll
        for (int j=0;j<KS;++j){
            int ch = 2 + c*KS + j;
            float a=aA[ch], d=aD[ch];
            float4 hv;
            hv.x=fmaxf(fmaf(a,pr[j+0],d),0.f);
            hv.y=fmaxf(fmaf(a,pr[j+1],d),0.f);
            hv.z=fmaxf(fmaf(a,pr[j+2],d),0.f);
            hv.w=fmaxf(fmaf(a,pr[j+3],d),0.f);
            #pragma unroll
            for (int o=0;o<IMC;++o) FMA4(tacc[o], w1[o*CATC+ch], hv);
        }
    }
    double vals[8];
    #pragma unroll
    for (int o=0;o<IMC;++o){
        *(float4*)(tbuf + ((size_t)(b*IMC+o))*Ln + l) = tacc[o];
        float4 v = tacc[o];
        vals[o]   = (double)v.x+v.y+v.z+v.w;
        vals[4+o] = (double)v.x*v.x+(double)v.y*v.y+(double)v.z*v.z+(double)v.w*v.w;
    }
    const int lane=tid&63, wid=tid>>6;
    #pragma unroll
    for (int i=0;i<8;++i){ double r=wredd(vals[i]); if(lane==0) rbuf[wid][i]=r; }
    __syncthreads();
    if (tid<8) atomAddD(&stats[S_T+tid], rbuf[0][tid]+rbuf[1][tid]+rbuf[2][tid]+rbuf[3][tid]);
}

__global__ void __launch_bounds__(TPB) k5(
    const float* __restrict__ tbuf, const float* __restrict__ beta,
    const float* __restrict__ w_cw2, const float* __restrict__ b_cw2,
    const float* __restrict__ g_im, const float* __restrict__ be_im,
    float* __restrict__ ap, double* __restrict__ stats)
{
    __shared__ float aA[IMC], aD[IMC], w2[OC*IMC], b2[OC];
    __shared__ double rbuf[4][16];
    const int tid=threadIdx.x;
    if (tid==0){
        const double N=(double)NPOS;
        for (int i=0;i<IMC;++i){
            double m=stats[S_T+i]/N, v=stats[SS_T+i]/N - m*m;
            double inv=1.0/sqrt(v+1e-5);
            aA[i]=(float)(g_im[i]*inv); aD[i]=be_im[i]-(float)(m*inv*g_im[i]);
        }
    }
    if (tid<OC*IMC) w2[tid]=w_cw2[tid];
    if (tid<OC)     b2[tid]=b_cw2[tid];
    __syncthreads();
    const int b=blockIdx.x/TILES, tile=blockIdx.x%TILES;
    const int l = tile*PPB + tid*VPT;
    float4 h2[IMC];
    #pragma unroll
    for (int i=0;i<IMC;++i){
        float4 tv = *(const float4*)(tbuf + ((size_t)(b*IMC+i))*Ln + l);
        h2[i] = affrelu(tv, aA[i], aD[i]);
    }
    double vals[16];
    #pragma unroll
    for (int o=0;o<OC;++o){
        float bb=b2[o];
        float4 w=make_float4(bb,bb,bb,bb);
        #pragma unroll
        for (int i=0;i<IMC;++i) FMA4(w, w2[o*IMC+i], h2[i]);
        float4 bv = *(const float4*)(beta + ((size_t)(b*OC+o))*Ln + l);
        float4 av; av.x=w.x*bv.x; av.y=w.y*bv.y; av.z=w.z*bv.z; av.w=w.w*bv.w;
        *(float4*)(ap + ((size_t)(b*OC+o))*Ln + l) = av;
        vals[o]   = (double)av.x+av.y+av.z+av.w;
        vals[8+o] = (double)av.x*av.x+(double)av.y*av.y+(double)av.z*av.z+(double)av.w*av.w;
    }
    const int lane=tid&63, wid=tid>>6;
    #pragma unroll
    for (int i=0;i<16;++i){ double r=wredd(vals[i]); if(lane==0) rbuf[wid][i]=r; }
    __syncthreads();
    if (tid<16) atomAddD(&stats[S_AP+tid], rbuf[0][tid]+rbuf[1][tid]+rbuf[2][tid]+rbuf[3][tid]);
}

__global__ void __launch_bounds__(TPB) k7(
    const float* __restrict__ x, const float* __restrict__ ap,
    const float* __restrict__ w_out, const float* __restrict__ b_out,
    const float* __restrict__ g_ag, const float* __restrict__ be_ag,
    double* __restrict__ stats)
{
    __shared__ float aA[OC], aD[OC], wo[Hc*OC], bo[Hc];
    __shared__ float fredS[Hc][4], fredQ[Hc][4];
    const int tid=threadIdx.x;
    if (tid==0){
        const double N=(double)NPOS;
        for (int o=0;o<OC;++o){
            double m=stats[S_AP+o]/N, v=stats[SS_AP+o]/N - m*m;
            double inv=1.0/sqrt(v+1e-5);
            aA[o]=(float)(g_ag[o]*inv); aD[o]=be_ag[o]-(float)(m*inv*g_ag[o]);
        }
    }
    if (tid<Hc*OC) wo[tid]=w_out[tid];
    if (tid<Hc)    bo[tid]=b_out[tid];
    __syncthreads();
    const int b=blockIdx.x/TILES, tile=blockIdx.x%TILES;
    const int l=tile*PPB+tid*VPT;
    float4 ag[OC];
    #pragma unroll
    for (int o=0;o<OC;++o){
        float4 av=*(const float4*)(ap+((size_t)(b*OC+o))*Ln+l);
        ag[o]=affrelu(av, aA[o], aD[o]);
    }
    const int lane=tid&63, wid=tid>>6;
    const float* xb = x + (size_t)b*Hc*Ln + l;
    #pragma unroll 4
    for (int h=0;h<Hc;++h){
        float4 y = *(const float4*)(xb + (size_t)h*Ln);
        float bb=bo[h]; y.x+=bb; y.y+=bb; y.z+=bb; y.w+=bb;
        #pragma unroll
        for (int o=0;o<OC;++o) FMA4(y, wo[h*OC+o], ag[o]);
        float fs=y.x+y.y+y.z+y.w;
        float fq=y.x*y.x+y.y*y.y+y.z*y.z+y.w*y.w;
        fs=wredf(fs); fq=wredf(fq);
        if (lane==0){ fredS[h][wid]=fs; fredQ[h][wid]=fq; }
    }
    __syncthreads();
    if (tid<Hc){
        double s=(double)fredS[tid][0]+fredS[tid][1]+fredS[tid][2]+fredS[tid][3];
        double q=(double)fredQ[tid][0]+fredQ[tid][1]+fredQ[tid][2]+fredQ[tid][3];
        atomAddD(&stats[S_Y +tid], s);
        atomAddD(&stats[SS_Y+tid], q);
    }
}

__global__ void __launch_bounds__(TPB) k9(
    const float* __restrict__ x, const float* __restrict__ ap,
    const float* __restrict__ w_out, const float* __restrict__ b_out,
    const float* __restrict__ g_ag, const float* __restrict__ be_ag,
    const float* __restrict__ g_hid, const float* __restrict__ be_hid,
    float* __restrict__ out, const double* __restrict__ stats)
{
    __shared__ float aA[OC], aD[OC], wo[Hc*OC], bo[Hc], hA[Hc], hD[Hc];
    const int tid=threadIdx.x;
    if (tid==0){
        const double N=(double)NPOS;
        for (int o=0;o<OC;++o){
            double m=stats[S_AP+o]/N, v=stats[SS_AP+o]/N - m*m;
            double inv=1.0/sqrt(v+1e-5);
            aA[o]=(float)(g_ag[o]*inv); aD[o]=be_ag[o]-(float)(m*inv*g_ag[o]);
        }
        for (int h=0;h<Hc;++h){
            double m=stats[S_Y+h]/N, v=stats[SS_Y+h]/N - m*m;
            double inv=1.0/sqrt(v+1e-5);
            hA[h]=(float)(g_hid[h]*inv); hD[h]=be_hid[h]-(float)(m*inv*g_hid[h]);
        }
    }
    if (tid<Hc*OC) wo[tid]=w_out[tid];
    if (tid<Hc)    bo[tid]=b_out[tid];
    __syncthreads();
    const int b=blockIdx.x/TILES, tile=blockIdx.x%TILES;
    const int l=tile*PPB+tid*VPT;
    float4 ag[OC];
    #pragma unroll
    for (int o=0;o<OC;++o){
        float4 av=*(const float4*)(ap+((size_t)(b*OC+o))*Ln+l);
        ag[o]=affrelu(av, aA[o], aD[o]);
    }
    const float* xb = x + (size_t)b*Hc*Ln + l;
    float* ob = out + (size_t)b*Hc*Ln + l;
    #pragma unroll 4
    for (int h=0;h<Hc;++h){
        float4 y = *(const float4*)(xb + (size_t)h*Ln);
        float bb=bo[h]; y.x+=bb; y.y+=bb; y.z+=bb; y.w+=bb;
        #pragma unroll
        for (int o=0;o<OC;++o) FMA4(y, wo[h*OC+o], ag[o]);
        *(float4*)(ob + (size_t)h*Ln) = affrelu(y, hA[h], hD[h]);
    }
}

extern "C" void kernel_launch(void* const* d_in, const int* in_sizes, int n_in,
                              void* d_out, int out_size, void* d_ws, size_t ws_size,
                              hipStream_t stream)
{
    const float* x     =(const float*)d_in[0];
    const float* w_phi =(const float*)d_in[1];  const float* b_phi =(const float*)d_in[2];
    const float* w_psi =(const float*)d_in[3];  const float* b_psi =(const float*)d_in[4];
    const float* w_beta=(const float*)d_in[5];  const float* b_beta=(const float*)d_in[6];
    const float* w_cw1 =(const float*)d_in[7];  const float* b_cw1 =(const float*)d_in[8];
    const float* w_cw2 =(const float*)d_in[9];  const float* b_cw2 =(const float*)d_in[10];
    const float* w_out =(const float*)d_in[11]; const float* b_out =(const float*)d_in[12];
    const float* g_cat =(const float*)d_in[13]; const float* be_cat=(const float*)d_in[14];
    const float* g_im  =(const float*)d_in[15]; const float* be_im =(const float*)d_in[16];
    const float* g_ag  =(const float*)d_in[17]; const float* be_ag =(const float*)d_in[18];
    const float* g_hid =(const float*)d_in[19]; const float* be_hid=(const float*)d_in[20];

    // overlaid workspace layouts (only one path executes per call)
    //   coop:     stats [0,32768) | bstats [32768,32960) | halo [40960, +64KiB)
    //   fallback: stats [0,960)   | phi @ +1024 | psi | beta | tb | ap  (96 MiB)
    hipMemsetAsync(d_ws, 0, 33024, stream);

    P p;
    p.x=x; p.w_phi=w_phi; p.b_phi=b_phi; p.w_psi=w_psi; p.b_psi=b_psi;
    p.w_beta=w_beta; p.b_beta=b_beta; p.w_cw1=w_cw1; p.b_cw1=b_cw1;
    p.w_cw2=w_cw2; p.b_cw2=b_cw2; p.w_out=w_out; p.b_out=b_out;
    p.g_cat=g_cat; p.be_cat=be_cat; p.g_im=g_im; p.be_im=be_im;
    p.g_ag=g_ag; p.be_ag=be_ag; p.g_hid=g_hid; p.be_hid=be_hid;
    p.out=(float*)d_out;
    p.stats  = (double*)d_ws;
    p.bstats = p.stats + (size_t)NSLOT*SSTR;
    p.halo   = (float*)((char*)d_ws + 40960);

    bool coop_ok = false;
    int dev = 0, nCU = 0, maxb = 0;
    if (hipGetDevice(&dev) == hipSuccess &&
        hipDeviceGetAttribute(&nCU, hipDeviceAttributeMultiprocessorCount, dev) == hipSuccess &&
        hipOccupancyMaxActiveBlocksPerMultiprocessor(&maxb, fused, TPB, 0) == hipSuccess &&
        (long)maxb * (long)nCU >= (long)NBLK)
    {
        void* args[] = { &p };
        if (hipLaunchCooperativeKernel(fused, dim3(NBLK), dim3(TPB), args, 0u, stream) == hipSuccess)
            coop_ok = true;
    }

    if (!coop_ok) {
        double* stats = (double*)d_ws;
        float*  fb    = (float*)d_ws;
        float* phi  = fb + 256;
        float* psi  = phi  + (size_t)Bn*RELC*Ln;
        float* beta = psi  + (size_t)Bn*RELC*Ln;
        float* tb   = beta + (size_t)Bn*OC*Ln;
        float* ap   = tb   + (size_t)Bn*IMC*Ln;
        k1<<<NBLK, TPB, 0, stream>>>(x, w_phi,b_phi, w_psi,b_psi, w_beta,b_beta, phi,psi,beta, stats);
        k3<<<NBLK, TPB, 0, stream>>>(phi,psi, w_cw1,b_cw1, g_cat,be_cat, tb, stats);
        k5<<<NBLK, TPB, 0, stream>>>(tb,beta, w_cw2,b_cw2, g_im,be_im, ap, stats);
        k7<<<NBLK, TPB, 0, stream>>>(x,ap, w_out,b_out, g_ag,be_ag, stats);
        k9<<<NBLK, TPB, 0, stream>>>(x,ap, w_out,b_out, g_ag,be_ag, g_hid,be_hid, (float*)d_out, stats);
    }
}

// Round 4
// 195.741 us; speedup vs baseline: 1.1376x; 1.1376x over previous
//
#include <hip/hip_runtime.h>
#include <math.h>

#define Bn 32
#define Hc 32
#define Ln 32768
#define RELC 2
#define IMC 4
#define OC 8
#define CATC 16
#define KS 7
#define NPOS (Bn*Ln)
#define TPB 256
#define VPT 4
#define PPB (TPB*VPT)          // 1024 positions per block
#define TILES (Ln/PPB)         // 32
#define NBLK (Bn*TILES)        // 1024 blocks
#define NSLOT 8
#define SSTR 128               // doubles per stat slot (8 slots -> 8 KiB)

// slot-relative stat indices
#define iS_PHI  0   // [0..1]
#define iSS_PHI 2   // [2..3]
#define iS_PSI  4   // [4..5]
#define iSS_PSI 6   // [6..7]
#define iS_T    8   // [8..11]
#define iSS_T   12  // [12..15]
#define iS_AP   16  // [16..23]
#define iSS_AP  24  // [24..31]
#define iS_Y    32  // [32..63]
#define iSS_Y   64  // [64..95]
// bstats (psi boundary corrections, unslotted; after the 8 slots)
#define bPF  0
#define bPFS 6
#define bQL  12
#define bQLS 18
#define NBST 24

#define FMA4(A,S,V) { A.x=fmaf((S),(V).x,A.x); A.y=fmaf((S),(V).y,A.y); A.z=fmaf((S),(V).z,A.z); A.w=fmaf((S),(V).w,A.w); }

__device__ inline float4 affrelu(float4 v, float a, float d){
    float4 r;
    r.x=fmaxf(fmaf(a,v.x,d),0.f); r.y=fmaxf(fmaf(a,v.y,d),0.f);
    r.z=fmaxf(fmaf(a,v.z,d),0.f); r.w=fmaxf(fmaf(a,v.w,d),0.f);
    return r;
}
__device__ inline double wredd(double v){
    #pragma unroll
    for (int o=32;o>0;o>>=1) v += __shfl_down(v,o,64);
    return v;
}
__device__ inline float wredf(float v){
    #pragma unroll
    for (int o=32;o>0;o>>=1) v += __shfl_down(v,o,64);
    return v;
}
__device__ inline void atomAddD(double* p, double v){ unsafeAtomicAdd(p, v); }

// =================== k1: x -> phi,psi,beta + phi/psi stats ===================
__global__ void __launch_bounds__(TPB) k1(
    const float* __restrict__ x,
    const float* __restrict__ w_phi, const float* __restrict__ b_phi,
    const float* __restrict__ w_psi, const float* __restrict__ b_psi,
    const float* __restrict__ w_beta,const float* __restrict__ b_beta,
    float* __restrict__ phi, float* __restrict__ psi, float* __restrict__ beta,
    double* __restrict__ stats, double* __restrict__ bstats)
{
    __shared__ __align__(16) float wl[Hc*12 + 12];
    __shared__ double rbuf[4][8];
    const int tid = threadIdx.x;
    for (int i = tid; i < Hc*12; i += TPB) {
        int h = i/12, j = i%12;
        float v;
        if (j < 2)      v = w_phi[j*Hc + h];
        else if (j < 4) v = w_psi[(j-2)*Hc + h];
        else            v = w_beta[(j-4)*Hc + h];
        wl[h*12 + j] = v;
    }
    if (tid < 12)
        wl[Hc*12+tid] = (tid<2) ? b_phi[tid] : (tid<4) ? b_psi[tid-2] : b_beta[tid-4];
    __syncthreads();

    const int b    = blockIdx.x / TILES;
    const int tile = blockIdx.x % TILES;
    const int l0   = tile*PPB + tid*VPT;
    double* st = stats + (size_t)(blockIdx.x & (NSLOT-1))*SSTR;

    float4 acc[12];
    #pragma unroll
    for (int j=0;j<12;++j){ float bb = wl[Hc*12+j]; acc[j]=make_float4(bb,bb,bb,bb); }

    const float* xb = x + (size_t)b*Hc*Ln + l0;
    #pragma unroll 4
    for (int h=0; h<Hc; ++h) {
        const float4 xv = *(const float4*)(xb + (size_t)h*Ln);
        const float4 w0 = *(const float4*)(&wl[h*12+0]);
        const float4 w1 = *(const float4*)(&wl[h*12+4]);
        const float4 w2 = *(const float4*)(&wl[h*12+8]);
        FMA4(acc[0],w0.x,xv); FMA4(acc[1],w0.y,xv); FMA4(acc[2],w0.z,xv); FMA4(acc[3],w0.w,xv);
        FMA4(acc[4],w1.x,xv); FMA4(acc[5],w1.y,xv); FMA4(acc[6],w1.z,xv); FMA4(acc[7],w1.w,xv);
        FMA4(acc[8],w2.x,xv); FMA4(acc[9],w2.y,xv); FMA4(acc[10],w2.z,xv); FMA4(acc[11],w2.w,xv);
    }
    #pragma unroll
    for (int c=0;c<RELC;++c) *(float4*)(phi + ((size_t)(b*RELC+c))*Ln + l0) = acc[c];
    #pragma unroll
    for (int c=0;c<RELC;++c) *(float4*)(psi + ((size_t)(b*RELC+c))*Ln + l0) = acc[2+c];
    #pragma unroll
    for (int o=0;o<OC;++o)   *(float4*)(beta + ((size_t)(b*OC+o))*Ln + l0)  = acc[4+o];

    double vals[8];
    #pragma unroll
    for (int c=0;c<2;++c){
        float4 v = acc[c];
        vals[c]   = (double)v.x+v.y+v.z+v.w;
        vals[2+c] = (double)v.x*v.x+(double)v.y*v.y+(double)v.z*v.z+(double)v.w*v.w;
        float4 u = acc[2+c];
        vals[4+c] = (double)u.x+u.y+u.z+u.w;
        vals[6+c] = (double)u.x*u.x+(double)u.y*u.y+(double)u.z*u.z+(double)u.w*u.w;
    }
    if (tile==0 || tile==TILES-1) {
        #pragma unroll
        for (int c=0;c<2;++c){
            const float pv[4] = {acc[2+c].x, acc[2+c].y, acc[2+c].z, acc[2+c].w};
            #pragma unroll
            for (int e=0;e<4;++e){
                int le = l0+e;
                if (le < 3) {
                    atomAddD(&bstats[bPF +c*3+le], (double)pv[e]);
                    atomAddD(&bstats[bPFS+c*3+le], (double)pv[e]*pv[e]);
                }
                if (le >= Ln-3) {
                    int i = le-(Ln-3);
                    atomAddD(&bstats[bQL +c*3+i], (double)pv[e]);
                    atomAddD(&bstats[bQLS+c*3+i], (double)pv[e]*pv[e]);
                }
            }
        }
    }
    const int lane=tid&63, wid=tid>>6;
    #pragma unroll
    for (int i=0;i<8;++i){ double r=wredd(vals[i]); if(lane==0) rbuf[wid][i]=r; }
    __syncthreads();
    if (tid<8) atomAddD(&st[iS_PHI+tid], rbuf[0][tid]+rbuf[1][tid]+rbuf[2][tid]+rbuf[3][tid]);
}

// helper: compute BN_cat affine (threads tid<16)
#define CAT_AFFINE(aCat,dCat)                                                              \
    if (tid < CATC){                                                                       \
        int ch=tid; double S=0,SS=0;                                                       \
        if (ch<2){                                                                         \
            for (int s=0;s<NSLOT;++s){ S+=stats[(size_t)s*SSTR+iS_PHI+ch]; SS+=stats[(size_t)s*SSTR+iSS_PHI+ch]; } \
        } else {                                                                           \
            int c=(ch-2)/KS, j=(ch-2)%KS, d=j-KS/2;                                        \
            for (int s=0;s<NSLOT;++s){ S+=stats[(size_t)s*SSTR+iS_PSI+c]; SS+=stats[(size_t)s*SSTR+iSS_PSI+c]; }   \
            if (d>0) for (int i=0;i<d;++i)   { S-=bstats[bPF+c*3+i];  SS-=bstats[bPFS+c*3+i]; } \
            if (d<0) for (int i=3+d;i<3;++i) { S-=bstats[bQL+c*3+i];  SS-=bstats[bQLS+c*3+i]; } \
        }                                                                                  \
        double m=S/N, v=SS/N-m*m, inv=1.0/sqrt(v+1e-5);                                    \
        aCat[ch]=(float)(g_cat[ch]*inv);                                                   \
        dCat[ch]=be_cat[ch]-(float)(m*inv*g_cat[ch]);                                      \
    }

// helper: stage psi tile into LDS (positions lb-3 .. lb+1026 at idx 0..1029)
#define STAGE_PSI(psiT)                                                                    \
    _Pragma("unroll")                                                                      \
    for (int c=0;c<2;++c)                                                                  \
        for (int idx=tid; idx<1032; idx+=TPB) {                                            \
            int l = lb - 3 + idx;                                                          \
            psiT[c][idx] = (l>=0 && l<Ln && idx<1030) ? psi[((size_t)(b*RELC+c))*Ln + l] : 0.f; \
        }

// helper: compute tacc[IMC] (float4 each) from phi + psiT  (round-1 k3 body)
#define COMPUTE_T(tacc,aCat,dCat,w1s,b1s,psiT)                                             \
    _Pragma("unroll")                                                                      \
    for (int o=0;o<IMC;++o){ float bb=b1s[o]; tacc[o]=make_float4(bb,bb,bb,bb); }          \
    _Pragma("unroll")                                                                      \
    for (int c=0;c<RELC;++c){                                                              \
        float4 pv = *(const float4*)(phi + ((size_t)(b*RELC+c))*Ln + lb + li);             \
        float4 hv = affrelu(pv, aCat[c], dCat[c]);                                         \
        _Pragma("unroll")                                                                  \
        for (int o=0;o<IMC;++o) FMA4(tacc[o], w1s[o*CATC+c], hv);                          \
    }                                                                                      \
    _Pragma("unroll")                                                                      \
    for (int c=0;c<RELC;++c){                                                              \
        float4 A  = *(const float4*)&psiT[c][li];                                          \
        float4 Bv = *(const float4*)&psiT[c][li+4];                                        \
        float4 Cv = *(const float4*)&psiT[c][li+8];                                        \
        float pr[12] = {A.x,A.y,A.z,A.w, Bv.x,Bv.y,Bv.z,Bv.w, Cv.x,Cv.y,Cv.z,Cv.w};        \
        _Pragma("unroll")                                                                  \
        for (int j=0;j<KS;++j){                                                            \
            int ch = 2 + c*KS + j;                                                         \
            float a=aCat[ch], d=dCat[ch];                                                  \
            float4 hv;                                                                     \
            hv.x=fmaxf(fmaf(a,pr[j+0],d),0.f);                                             \
            hv.y=fmaxf(fmaf(a,pr[j+1],d),0.f);                                             \
            hv.z=fmaxf(fmaf(a,pr[j+2],d),0.f);                                             \
            hv.w=fmaxf(fmaf(a,pr[j+3],d),0.f);                                             \
            _Pragma("unroll")                                                              \
            for (int o=0;o<IMC;++o) FMA4(tacc[o], w1s[o*CATC+ch], hv);                     \
        }                                                                                  \
    }

// =================== k3t: t-stats only (no writes) ===================
__global__ void __launch_bounds__(TPB) k3t(
    const float* __restrict__ phi, const float* __restrict__ psi,
    const float* __restrict__ w_cw1, const float* __restrict__ b_cw1,
    const float* __restrict__ g_cat, const float* __restrict__ be_cat,
    double* __restrict__ stats, const double* __restrict__ bstats)
{
    __shared__ float aCat[CATC], dCat[CATC];
    __shared__ float w1s[IMC*CATC], b1s[IMC];
    __shared__ __align__(16) float psiT[2][1032];
    __shared__ double rbuf[4][8];
    const int tid = threadIdx.x;
    const double N = (double)NPOS;
    const int b    = blockIdx.x / TILES;
    const int tile = blockIdx.x % TILES;
    const int lb   = tile*PPB;
    const int li   = tid*VPT;
    double* st = stats + (size_t)(blockIdx.x & (NSLOT-1))*SSTR;

    CAT_AFFINE(aCat,dCat)
    if (tid < IMC*CATC) w1s[tid] = w_cw1[tid];
    if (tid < IMC)      b1s[tid] = b_cw1[tid];
    STAGE_PSI(psiT)
    __syncthreads();

    float4 tacc[IMC];
    COMPUTE_T(tacc,aCat,dCat,w1s,b1s,psiT)

    double vals[8];
    #pragma unroll
    for (int o=0;o<IMC;++o){
        float4 v = tacc[o];
        vals[o]   = (double)v.x+v.y+v.z+v.w;
        vals[4+o] = (double)v.x*v.x+(double)v.y*v.y+(double)v.z*v.z+(double)v.w*v.w;
    }
    const int lane=tid&63, wid=tid>>6;
    #pragma unroll
    for (int i=0;i<8;++i){ double r=wredd(vals[i]); if(lane==0) rbuf[wid][i]=r; }
    __syncthreads();
    if (tid<8) atomAddD(&st[iS_T+tid], rbuf[0][tid]+rbuf[1][tid]+rbuf[2][tid]+rbuf[3][tid]);
}

// =================== k5a: recompute t -> ap-stats only ===================
__global__ void __launch_bounds__(TPB) k5a(
    const float* __restrict__ phi, const float* __restrict__ psi,
    const float* __restrict__ beta,
    const float* __restrict__ w_cw1, const float* __restrict__ b_cw1,
    const float* __restrict__ w_cw2, const float* __restrict__ b_cw2,
    const float* __restrict__ g_cat, const float* __restrict__ be_cat,
    const float* __restrict__ g_im,  const float* __restrict__ be_im,
    double* __restrict__ stats, const double* __restrict__ bstats)
{
    __shared__ float aCat[CATC], dCat[CATC], aIm[IMC], dIm[IMC];
    __shared__ float w1s[IMC*CATC], b1s[IMC], w2s[OC*IMC], b2s[OC];
    __shared__ __align__(16) float psiT[2][1032];
    __shared__ double rbuf[4][16];
    const int tid = threadIdx.x;
    const double N = (double)NPOS;
    const int b    = blockIdx.x / TILES;
    const int tile = blockIdx.x % TILES;
    const int lb   = tile*PPB;
    const int li   = tid*VPT;
    double* st = stats + (size_t)(blockIdx.x & (NSLOT-1))*SSTR;

    CAT_AFFINE(aCat,dCat)
    if (tid>=32 && tid<32+IMC){
        int i=tid-32; double S=0,SS=0;
        for (int s=0;s<NSLOT;++s){ S+=stats[(size_t)s*SSTR+iS_T+i]; SS+=stats[(size_t)s*SSTR+iSS_T+i]; }
        double m=S/N, v=SS/N-m*m, inv=1.0/sqrt(v+1e-5);
        aIm[i]=(float)(g_im[i]*inv); dIm[i]=be_im[i]-(float)(m*inv*g_im[i]);
    }
    if (tid < IMC*CATC) w1s[tid] = w_cw1[tid];
    if (tid < IMC)      b1s[tid] = b_cw1[tid];
    if (tid>=64 && tid<64+OC*IMC) w2s[tid-64]=w_cw2[tid-64];
    if (tid>=96 && tid<96+OC)     b2s[tid-96]=b_cw2[tid-96];
    STAGE_PSI(psiT)
    __syncthreads();

    float4 tacc[IMC];
    COMPUTE_T(tacc,aCat,dCat,w1s,b1s,psiT)

    double vals[16];
    {
        float4 h2[IMC];
        #pragma unroll
        for (int i=0;i<IMC;++i) h2[i]=affrelu(tacc[i],aIm[i],dIm[i]);
        #pragma unroll
        for (int o=0;o<OC;++o){
            float bb=b2s[o];
            float4 w=make_float4(bb,bb,bb,bb);
            #pragma unroll
            for (int i=0;i<IMC;++i) FMA4(w,w2s[o*IMC+i],h2[i]);
            float4 bv = *(const float4*)(beta + ((size_t)(b*OC+o))*Ln + lb + li);
            float4 av; av.x=w.x*bv.x; av.y=w.y*bv.y; av.z=w.z*bv.z; av.w=w.w*bv.w;
            vals[o]   = (double)av.x+av.y+av.z+av.w;
            vals[8+o] = (double)av.x*av.x+(double)av.y*av.y+(double)av.z*av.z+(double)av.w*av.w;
        }
    }
    const int lane=tid&63, wid=tid>>6;
    #pragma unroll
    for (int i=0;i<16;++i){ double r=wredd(vals[i]); if(lane==0) rbuf[wid][i]=r; }
    __syncthreads();
    if (tid<16) atomAddD(&st[iS_AP+tid], rbuf[0][tid]+rbuf[1][tid]+rbuf[2][tid]+rbuf[3][tid]);
}

// =================== k7y: recompute -> ag; + x -> y-stats ===================
__global__ void __launch_bounds__(TPB) k7y(
    const float* __restrict__ x,
    const float* __restrict__ phi, const float* __restrict__ psi,
    const float* __restrict__ beta,
    const float* __restrict__ w_cw1, const float* __restrict__ b_cw1,
    const float* __restrict__ w_cw2, const float* __restrict__ b_cw2,
    const float* __restrict__ w_out, const float* __restrict__ b_out,
    const float* __restrict__ g_cat, const float* __restrict__ be_cat,
    const float* __restrict__ g_im,  const float* __restrict__ be_im,
    const float* __restrict__ g_ag,  const float* __restrict__ be_ag,
    double* __restrict__ stats, const double* __restrict__ bstats)
{
    __shared__ float aCat[CATC], dCat[CATC], aIm[IMC], dIm[IMC], aAg[OC], dAg[OC];
    __shared__ float w1s[IMC*CATC], b1s[IMC], w2s[OC*IMC], b2s[OC];
    __shared__ __align__(16) float wos[Hc*OC];
    __shared__ float bos[Hc];
    __shared__ __align__(16) float psiT[2][1032];
    __shared__ float fredS[Hc][4], fredQ[Hc][4];
    const int tid = threadIdx.x;
    const double N = (double)NPOS;
    const int b    = blockIdx.x / TILES;
    const int tile = blockIdx.x % TILES;
    const int lb   = tile*PPB;
    const int li   = tid*VPT;
    double* st = stats + (size_t)(blockIdx.x & (NSLOT-1))*SSTR;

    CAT_AFFINE(aCat,dCat)
    if (tid>=32 && tid<32+IMC){
        int i=tid-32; double S=0,SS=0;
        for (int s=0;s<NSLOT;++s){ S+=stats[(size_t)s*SSTR+iS_T+i]; SS+=stats[(size_t)s*SSTR+iSS_T+i]; }
        double m=S/N, v=SS/N-m*m, inv=1.0/sqrt(v+1e-5);
        aIm[i]=(float)(g_im[i]*inv); dIm[i]=be_im[i]-(float)(m*inv*g_im[i]);
    }
    if (tid>=48 && tid<48+OC){
        int o=tid-48; double S=0,SS=0;
        for (int s=0;s<NSLOT;++s){ S+=stats[(size_t)s*SSTR+iS_AP+o]; SS+=stats[(size_t)s*SSTR+iSS_AP+o]; }
        double m=S/N, v=SS/N-m*m, inv=1.0/sqrt(v+1e-5);
        aAg[o]=(float)(g_ag[o]*inv); dAg[o]=be_ag[o]-(float)(m*inv*g_ag[o]);
    }
    if (tid < IMC*CATC) w1s[tid] = w_cw1[tid];
    if (tid < IMC)      b1s[tid] = b_cw1[tid];
    if (tid>=64 && tid<64+OC*IMC) w2s[tid-64]=w_cw2[tid-64];
    if (tid>=96 && tid<96+OC)     b2s[tid-96]=b_cw2[tid-96];
    wos[tid] = w_out[tid];                                  // Hc*OC == 256
    if (tid>=128 && tid<128+Hc) bos[tid-128]=b_out[tid-128];
    STAGE_PSI(psiT)
    __syncthreads();

    float4 tacc[IMC];
    COMPUTE_T(tacc,aCat,dCat,w1s,b1s,psiT)

    float4 ag[OC];
    {
        float4 h2[IMC];
        #pragma unroll
        for (int i=0;i<IMC;++i) h2[i]=affrelu(tacc[i],aIm[i],dIm[i]);
        #pragma unroll
        for (int o=0;o<OC;++o){
            float bb=b2s[o];
            float4 w=make_float4(bb,bb,bb,bb);
            #pragma unroll
            for (int i=0;i<IMC;++i) FMA4(w,w2s[o*IMC+i],h2[i]);
            float4 bv = *(const float4*)(beta + ((size_t)(b*OC+o))*Ln + lb + li);
            float4 av; av.x=w.x*bv.x; av.y=w.y*bv.y; av.z=w.z*bv.z; av.w=w.w*bv.w;
            ag[o]=affrelu(av, aAg[o], dAg[o]);
        }
    }
    const int lane=tid&63, wid=tid>>6;
    const float* xb = x + (size_t)b*Hc*Ln + lb + li;
    #pragma unroll 4
    for (int h=0;h<Hc;++h){
        float4 y = *(const float4*)(xb + (size_t)h*Ln);
        float bb=bos[h]; y.x+=bb; y.y+=bb; y.z+=bb; y.w+=bb;
        #pragma unroll
        for (int o=0;o<OC;++o) FMA4(y, wos[h*OC+o], ag[o]);
        float fs=y.x+y.y+y.z+y.w;
        float fq=y.x*y.x+y.y*y.y+y.z*y.z+y.w*y.w;
        fs=wredf(fs); fq=wredf(fq);
        if (lane==0){ fredS[h][wid]=fs; fredQ[h][wid]=fq; }
    }
    __syncthreads();
    if (tid<Hc){
        double s=(double)fredS[tid][0]+fredS[tid][1]+fredS[tid][2]+fredS[tid][3];
        double q=(double)fredQ[tid][0]+fredQ[tid][1]+fredQ[tid][2]+fredQ[tid][3];
        atomAddD(&st[iS_Y +tid], s);
        atomAddD(&st[iSS_Y+tid], q);
    }
}

// =================== k9o: recompute -> out ===================
__global__ void __launch_bounds__(TPB) k9o(
    const float* __restrict__ x,
    const float* __restrict__ phi, const float* __restrict__ psi,
    const float* __restrict__ beta,
    const float* __restrict__ w_cw1, const float* __restrict__ b_cw1,
    const float* __restrict__ w_cw2, const float* __restrict__ b_cw2,
    const float* __restrict__ w_out, const float* __restrict__ b_out,
    const float* __restrict__ g_cat, const float* __restrict__ be_cat,
    const float* __restrict__ g_im,  const float* __restrict__ be_im,
    const float* __restrict__ g_ag,  const float* __restrict__ be_ag,
    const float* __restrict__ g_hid, const float* __restrict__ be_hid,
    float* __restrict__ out,
    const double* __restrict__ stats, const double* __restrict__ bstats)
{
    __shared__ float aCat[CATC], dCat[CATC], aIm[IMC], dIm[IMC], aAg[OC], dAg[OC];
    __shared__ float aHid[Hc], dHid[Hc];
    __shared__ float w1s[IMC*CATC], b1s[IMC], w2s[OC*IMC], b2s[OC];
    __shared__ __align__(16) float wos[Hc*OC];
    __shared__ float bos[Hc];
    __shared__ __align__(16) float psiT[2][1032];
    const int tid = threadIdx.x;
    const double N = (double)NPOS;
    const int b    = blockIdx.x / TILES;
    const int tile = blockIdx.x % TILES;
    const int lb   = tile*PPB;
    const int li   = tid*VPT;

    CAT_AFFINE(aCat,dCat)
    if (tid>=32 && tid<32+IMC){
        int i=tid-32; double S=0,SS=0;
        for (int s=0;s<NSLOT;++s){ S+=stats[(size_t)s*SSTR+iS_T+i]; SS+=stats[(size_t)s*SSTR+iSS_T+i]; }
        double m=S/N, v=SS/N-m*m, inv=1.0/sqrt(v+1e-5);
        aIm[i]=(float)(g_im[i]*inv); dIm[i]=be_im[i]-(float)(m*inv*g_im[i]);
    }
    if (tid>=48 && tid<48+OC){
        int o=tid-48; double S=0,SS=0;
        for (int s=0;s<NSLOT;++s){ S+=stats[(size_t)s*SSTR+iS_AP+o]; SS+=stats[(size_t)s*SSTR+iSS_AP+o]; }
        double m=S/N, v=SS/N-m*m, inv=1.0/sqrt(v+1e-5);
        aAg[o]=(float)(g_ag[o]*inv); dAg[o]=be_ag[o]-(float)(m*inv*g_ag[o]);
    }
    if (tid>=160 && tid<160+Hc){
        int h=tid-160; double S=0,SS=0;
        for (int s=0;s<NSLOT;++s){ S+=stats[(size_t)s*SSTR+iS_Y+h]; SS+=stats[(size_t)s*SSTR+iSS_Y+h]; }
        double m=S/N, v=SS/N-m*m, inv=1.0/sqrt(v+1e-5);
        aHid[h]=(float)(g_hid[h]*inv); dHid[h]=be_hid[h]-(float)(m*inv*g_hid[h]);
    }
    if (tid < IMC*CATC) w1s[tid] = w_cw1[tid];
    if (tid < IMC)      b1s[tid] = b_cw1[tid];
    if (tid>=64 && tid<64+OC*IMC) w2s[tid-64]=w_cw2[tid-64];
    if (tid>=96 && tid<96+OC)     b2s[tid-96]=b_cw2[tid-96];
    wos[tid] = w_out[tid];
    if (tid>=128 && tid<128+Hc) bos[tid-128]=b_out[tid-128];
    STAGE_PSI(psiT)
    __syncthreads();

    float4 tacc[IMC];
    COMPUTE_T(tacc,aCat,dCat,w1s,b1s,psiT)

    float4 ag[OC];
    {
        float4 h2[IMC];
        #pragma unroll
        for (int i=0;i<IMC;++i) h2[i]=affrelu(tacc[i],aIm[i],dIm[i]);
        #pragma unroll
        for (int o=0;o<OC;++o){
            float bb=b2s[o];
            float4 w=make_float4(bb,bb,bb,bb);
            #pragma unroll
            for (int i=0;i<IMC;++i) FMA4(w,w2s[o*IMC+i],h2[i]);
            float4 bv = *(const float4*)(beta + ((size_t)(b*OC+o))*Ln + lb + li);
            float4 av; av.x=w.x*bv.x; av.y=w.y*bv.y; av.z=w.z*bv.z; av.w=w.w*bv.w;
            ag[o]=affrelu(av, aAg[o], dAg[o]);
        }
    }
    const float* xb = x + (size_t)b*Hc*Ln + lb + li;
    float* ob = out + (size_t)b*Hc*Ln + lb + li;
    #pragma unroll 4
    for (int h=0;h<Hc;++h){
        float4 y = *(const float4*)(xb + (size_t)h*Ln);
        float bb=bos[h]; y.x+=bb; y.y+=bb; y.z+=bb; y.w+=bb;
        #pragma unroll
        for (int o=0;o<OC;++o) FMA4(y, wos[h*OC+o], ag[o]);
        *(float4*)(ob + (size_t)h*Ln) = affrelu(y, aHid[h], dHid[h]);
    }
}

extern "C" void kernel_launch(void* const* d_in, const int* in_sizes, int n_in,
                              void* d_out, int out_size, void* d_ws, size_t ws_size,
                              hipStream_t stream)
{
    const float* x     =(const float*)d_in[0];
    const float* w_phi =(const float*)d_in[1];  const float* b_phi =(const float*)d_in[2];
    const float* w_psi =(const float*)d_in[3];  const float* b_psi =(const float*)d_in[4];
    const float* w_beta=(const float*)d_in[5];  const float* b_beta=(const float*)d_in[6];
    const float* w_cw1 =(const float*)d_in[7];  const float* b_cw1 =(const float*)d_in[8];
    const float* w_cw2 =(const float*)d_in[9];  const float* b_cw2 =(const float*)d_in[10];
    const float* w_out =(const float*)d_in[11]; const float* b_out =(const float*)d_in[12];
    const float* g_cat =(const float*)d_in[13]; const float* be_cat=(const float*)d_in[14];
    const float* g_im  =(const float*)d_in[15]; const float* be_im =(const float*)d_in[16];
    const float* g_ag  =(const float*)d_in[17]; const float* be_ag =(const float*)d_in[18];
    const float* g_hid =(const float*)d_in[19]; const float* be_hid=(const float*)d_in[20];

    double* stats  = (double*)d_ws;
    double* bstats = stats + (size_t)NSLOT*SSTR;
    float*  fbase  = (float*)((char*)d_ws + 16384);
    float* phi  = fbase;
    float* psi  = phi + (size_t)Bn*RELC*Ln;
    float* beta = psi + (size_t)Bn*RELC*Ln;

    hipMemsetAsync(d_ws, 0, ((size_t)NSLOT*SSTR + NBST)*sizeof(double), stream);
    k1 <<<NBLK, TPB, 0, stream>>>(x, w_phi,b_phi, w_psi,b_psi, w_beta,b_beta,
                                  phi,psi,beta, stats,bstats);
    k3t<<<NBLK, TPB, 0, stream>>>(phi,psi, w_cw1,b_cw1, g_cat,be_cat, stats,bstats);
    k5a<<<NBLK, TPB, 0, stream>>>(phi,psi,beta, w_cw1,b_cw1, w_cw2,b_cw2,
                                  g_cat,be_cat, g_im,be_im, stats,bstats);
    k7y<<<NBLK, TPB, 0, stream>>>(x, phi,psi,beta, w_cw1,b_cw1, w_cw2,b_cw2, w_out,b_out,
                                  g_cat,be_cat, g_im,be_im, g_ag,be_ag, stats,bstats);
    k9o<<<NBLK, TPB, 0, stream>>>(x, phi,psi,beta, w_cw1,b_cw1, w_cw2,b_cw2, w_out,b_out,
                                  g_cat,be_cat, g_im,be_im, g_ag,be_ag, g_hid,be_hid,
                                  (float*)d_out, stats,bstats);
}